// Round 2
// baseline (575.489 us; speedup 1.0000x reference)
//
#include <hip/hip_runtime.h>
#include <math.h>

#define HIDDEN 768
#define NHEADS 12
#define DHEAD  64
#define NB     8
#define LQ     512
#define LK     1024
#define LN_EPS 1e-12f
#define TS     1032   // bf16 shorts per S row (1024+8): stride 2064 B = 129 x 16B units

typedef __attribute__((ext_vector_type(8))) short short8;
typedef __attribute__((ext_vector_type(4))) float floatx4;

#define GLDS16(gp, lp) __builtin_amdgcn_global_load_lds( \
    (const __attribute__((address_space(1))) void*)(gp), \
    (__attribute__((address_space(3))) void*)(lp), 16, 0, 0)

__device__ __forceinline__ short f2bf(float f) {
    unsigned u = __float_as_uint(f);
    u = u + 0x7FFFu + ((u >> 16) & 1u);   // RNE
    return (short)(u >> 16);
}

__device__ __forceinline__ float bf2f(short s) {
    return __uint_as_float(((unsigned)(unsigned short)s) << 16);
}

// ---------------------------------------------------------------------------
// fp32 -> bf16 elementwise convert (n4 = n/4)
// ---------------------------------------------------------------------------
__global__ __launch_bounds__(256)
void cvt_f32_bf16(const float* __restrict__ in, short* __restrict__ out, int n4)
{
    int i = blockIdx.x * 256 + threadIdx.x;
    if (i >= n4) return;
    float4 v = ((const float4*)in)[i];
    short4 o;
    o.x = f2bf(v.x); o.y = f2bf(v.y); o.z = f2bf(v.z); o.w = f2bf(v.w);
    ((short4*)out)[i] = o;
}

// ---------------------------------------------------------------------------
// bf16 NT MFMA GEMM (128x128 tile, BK=32) - unchanged.
// ---------------------------------------------------------------------------
__global__ __launch_bounds__(256)
void gemm_nt_mfma(const short* __restrict__ A, const short* __restrict__ B,
                  float* __restrict__ Cf, short* __restrict__ Cb,
                  const float* __restrict__ bias, const float* __restrict__ res,
                  int K, int lda, int ldb, int ldc, float alpha)
{
    __shared__ short As[4096];
    __shared__ short Bs[4096];

    int n0 = blockIdx.x * 128;
    int m0 = blockIdx.y * 128;
    int t    = threadIdx.x;
    int lane = t & 63, wave = t >> 6;
    int quad = lane >> 4, l15 = lane & 15;
    int wr = wave >> 1, wc = wave & 1;

    int e0 = t, e1 = 256 + t;
    int r0 = e0 >> 2, c0 = (e0 & 3) ^ ((r0 >> 1) & 3);
    int r1 = e1 >> 2, c1 = (e1 & 3) ^ ((r1 >> 1) & 3);
    const short* Ap0 = A + (size_t)(m0 + r0) * lda + c0 * 8;
    const short* Ap1 = A + (size_t)(m0 + r1) * lda + c1 * 8;
    const short* Bp0 = B + (size_t)(n0 + r0) * ldb + c0 * 8;
    const short* Bp1 = B + (size_t)(n0 + r1) * ldb + c1 * 8;

    int aoff[4], boff[4];
#pragma unroll
    for (int i = 0; i < 4; i++) {
        int ra = wr * 64 + i * 16 + l15;
        aoff[i] = (ra * 4 + (quad ^ ((ra >> 1) & 3))) * 8;
        int rb = wc * 64 + i * 16 + l15;
        boff[i] = (rb * 4 + (quad ^ ((rb >> 1) & 3))) * 8;
    }

    floatx4 acc[4][4] = {};

    for (int k0 = 0; k0 < K; k0 += 32) {
        GLDS16(Ap0, &As[e0 * 8]);
        GLDS16(Ap1, &As[e1 * 8]);
        GLDS16(Bp0, &Bs[e0 * 8]);
        GLDS16(Bp1, &Bs[e1 * 8]);
        Ap0 += 32; Ap1 += 32; Bp0 += 32; Bp1 += 32;
        __syncthreads();

        short8 af[4], bfr[4];
#pragma unroll
        for (int i = 0; i < 4; i++) af[i]  = *(const short8*)&As[aoff[i]];
#pragma unroll
        for (int j = 0; j < 4; j++) bfr[j] = *(const short8*)&Bs[boff[j]];
#pragma unroll
        for (int i = 0; i < 4; i++)
#pragma unroll
            for (int j = 0; j < 4; j++)
                acc[i][j] = __builtin_amdgcn_mfma_f32_16x16x32_bf16(
                    af[i], bfr[j], acc[i][j], 0, 0, 0);
        __syncthreads();
    }

#pragma unroll
    for (int i = 0; i < 4; i++) {
        int mb = m0 + wr * 64 + i * 16 + quad * 4;
#pragma unroll
        for (int j = 0; j < 4; j++) {
            int n = n0 + wc * 64 + j * 16 + l15;
            float bv = bias ? bias[n] : 0.f;
#pragma unroll
            for (int r = 0; r < 4; r++) {
                int m = mb + r;
                float v = alpha * acc[i][j][r] + bv;
                if (res) v += res[(size_t)m * ldc + n];
                if (Cb) Cb[(size_t)m * ldc + n] = f2bf(v);
                else    Cf[(size_t)m * ldc + n] = v;
            }
        }
    }
}

// ---------------------------------------------------------------------------
// Transpose V proj: vb [B, LK, 768] -> vt [bh][64 d][1024 k]
// ---------------------------------------------------------------------------
__global__ __launch_bounds__(256)
void transpose_v(const short* __restrict__ vb, short* __restrict__ vt)
{
    __shared__ short T[256 * 72];   // 36 KB, pad 72 to break bank conflicts
    int kt = blockIdx.x, bh = blockIdx.y;
    int b = bh / 12, h = bh - b * 12;
    int t = threadIdx.x;
    const short* src = vb + ((size_t)b * LK + kt * 256) * HIDDEN + h * DHEAD;
#pragma unroll
    for (int it = 0; it < 8; it++) {
        int s = it * 256 + t;
        int k = s >> 3, c = s & 7;
        *(short8*)&T[k * 72 + c * 8] =
            *(const short8*)&src[(size_t)k * HIDDEN + c * 8];
    }
    __syncthreads();
    short* dst = vt + (size_t)bh * DHEAD * LK + kt * 256;
#pragma unroll
    for (int it = 0; it < 8; it++) {
        int s = it * 256 + t;
        int d = s >> 5, kc = s & 31;
        short8 v;
#pragma unroll
        for (int i = 0; i < 8; i++) v[i] = T[(kc * 8 + i) * 72 + d];
        *(short8*)&dst[(size_t)d * LK + kc * 8] = v;
    }
}

// ---------------------------------------------------------------------------
// Fused attention, 16-row Q tiles for occupancy:
//  - S resident in LDS as bf16, 16 rows x 1032 = 33 KB -> 4 blocks/CU
//    (16 waves/CU, ~50% occupancy; round-1 was 2 blocks/CU @ 64.5 KB)
//  - K and V B-fragments loaded straight from L2 (no staging barriers)
//  - XCD-locality remap: each XCD owns 12 bh (3 MB K+V, fits 4 MiB L2)
//  - grid 3072 blocks = exactly 3 waves of 1024 co-resident blocks
// ---------------------------------------------------------------------------
__global__ __launch_bounds__(256)
void fused_attn(const short* __restrict__ qb, const short* __restrict__ kb,
                const short* __restrict__ vt, const float* __restrict__ amask,
                float* __restrict__ probs, short* __restrict__ ctxb)
{
    __shared__ short S[16 * TS];           // 33 KB bf16 raw scores
    __shared__ float mpart[4][16];
    __shared__ float mrow[16], lrow[16];

    // XCD remap: consecutive flat ids round-robin XCDs (xcd = flat & 7).
    int flat = blockIdx.y * 32 + blockIdx.x;       // 0..3071
    int jj   = flat >> 3;                          // 0..383
    int bh   = (flat & 7) * 12 + jj % 12;
    int qt   = jj / 12;                            // 0..31
    int b = bh / 12, h = bh - b * 12;
    int m0 = qt * 16;

    const short* Qg = qb + ((size_t)b * LQ + m0) * HIDDEN + h * DHEAD;
    const short* Kg = kb + (size_t)b * LK * HIDDEN + h * DHEAD;
    const short* Vg = vt + (size_t)bh * DHEAD * LK;
    const float* Mg = amask + (size_t)b * LK;
    float* Pg = probs + (size_t)bh * LQ * LK + (size_t)m0 * LK;
    short* Cg = ctxb + ((size_t)b * LQ + m0) * HIDDEN + h * DHEAD;

    int t = threadIdx.x;
    int lane = t & 63, w = t >> 6;
    int quad = lane >> 4, l15 = lane & 15;

    // Q fragments straight from global (2 KB/block, L2-resident)
    // A-frag: row = l15, k = ks*32 + quad*8 + e
    short8 af[2];
#pragma unroll
    for (int ks = 0; ks < 2; ks++)
        af[ks] = *(const short8*)&Qg[(size_t)l15 * HIDDEN + ks * 32 + quad * 8];

    float mx[4];
#pragma unroll
    for (int r = 0; r < 4; r++) mx[r] = -3.0e38f;

    // ====== scores: barrier-free; wave w owns cols kc*64 + w*16 + l15 =====
#pragma unroll 4
    for (int kc = 0; kc < 16; kc++) {
        int n = kc * 64 + w * 16 + l15;
        const short* Kp = Kg + (size_t)n * HIDDEN;
        floatx4 acc = {};
#pragma unroll
        for (int ks = 0; ks < 2; ks++) {
            short8 bfr = *(const short8*)&Kp[ks * 32 + quad * 8];
            acc = __builtin_amdgcn_mfma_f32_16x16x32_bf16(
                af[ks], bfr, acc, 0, 0, 0);
        }
        float mk = Mg[n];
#pragma unroll
        for (int r = 0; r < 4; r++) {
            int m = quad * 4 + r;
            float v = acc[r] * 0.125f + mk;
            S[m * TS + n] = f2bf(v);
            mx[r] = fmaxf(mx[r], v);
        }
    }

    // row max: shuffle across l15 (cols within wave), LDS across waves
#pragma unroll
    for (int d = 1; d < 16; d <<= 1)
#pragma unroll
        for (int r = 0; r < 4; r++)
            mx[r] = fmaxf(mx[r], __shfl_xor(mx[r], d));
    if (l15 == 0)
#pragma unroll
        for (int r = 0; r < 4; r++)
            mpart[w][quad * 4 + r] = mx[r];
    __syncthreads();
    if (t < 16)
        mrow[t] = fmaxf(fmaxf(mpart[0][t], mpart[1][t]),
                        fmaxf(mpart[2][t], mpart[3][t]));
    __syncthreads();

    // ====== exp in place (bf16) + row sums; 16 lanes per row ==============
    {
        int r = t >> 4, seg = t & 15;
        float mr = mrow[r];
        float sum = 0.f;
#pragma unroll 4
        for (int i = 0; i < 8; i++) {
            int u = i * 16 + seg;  // consecutive lanes -> consecutive 16B units
            short8 v = *(const short8*)&S[r * TS + u * 8];
            short8 o;
#pragma unroll
            for (int e = 0; e < 8; e++) {
                float f = __expf(bf2f(v[e]) - mr);
                o[e] = f2bf(f);
                sum += f;
            }
            *(short8*)&S[r * TS + u * 8] = o;
        }
        sum += __shfl_xor(sum, 1);
        sum += __shfl_xor(sum, 2);
        sum += __shfl_xor(sum, 4);
        sum += __shfl_xor(sum, 8);
        if (seg == 0) lrow[r] = sum;
    }
    __syncthreads();

    // ====== probs: normalized fp32, one full row per iteration ============
#pragma unroll 2
    for (int r = 0; r < 16; r++) {
        float inv = 1.0f / lrow[r];
        short4 v = *(const short4*)&S[r * TS + t * 4];
        float4 o;
        o.x = bf2f(v.x) * inv; o.y = bf2f(v.y) * inv;
        o.z = bf2f(v.z) * inv; o.w = bf2f(v.w) * inv;
        ((float4*)(Pg + (size_t)r * LK))[t] = o;
    }

    // ====== PV: barrier-free; wave w owns output cols w*16 + l15 ==========
    floatx4 accO = {};
#pragma unroll 4
    for (int kc = 0; kc < 16; kc++) {
        short8 pa[2];
#pragma unroll
        for (int ks = 0; ks < 2; ks++)
            pa[ks] = *(const short8*)&S[l15 * TS + kc * 64 + ks * 32 + quad * 8];
#pragma unroll
        for (int ks = 0; ks < 2; ks++) {
            int n = w * 16 + l15;
            short8 bfr = *(const short8*)&Vg[(size_t)n * LK
                                             + kc * 64 + ks * 32 + quad * 8];
            accO = __builtin_amdgcn_mfma_f32_16x16x32_bf16(
                pa[ks], bfr, accO, 0, 0, 0);
        }
    }

    // ctx epilogue: rescale by 1/l, bf16 out
    int n = w * 16 + l15;
#pragma unroll
    for (int r = 0; r < 4; r++) {
        int m = quad * 4 + r;
        Cg[(size_t)m * HIDDEN + n] = f2bf(accO[r] / lrow[m]);
    }
}

// ---------------------------------------------------------------------------
// Row LayerNorm over HIDDEN=768; one block per row.
// ---------------------------------------------------------------------------
__global__ __launch_bounds__(256)
void layernorm_rows(const float* __restrict__ H, const float* __restrict__ gamma,
                    const float* __restrict__ beta, float* __restrict__ out)
{
    int row = blockIdx.x;
    const float* h = H + (long)row * HIDDEN;
    int t = threadIdx.x;

    float x[3];
    float s = 0.f, ss = 0.f;
#pragma unroll
    for (int i = 0; i < 3; i++) {
        x[i] = h[t + 256 * i];
        s  += x[i];
        ss += x[i] * x[i];
    }
#pragma unroll
    for (int off = 32; off > 0; off >>= 1) {
        s  += __shfl_down(s, off);
        ss += __shfl_down(ss, off);
    }
    __shared__ float sh_s[4], sh_ss[4];
    int wave = t >> 6;
    if ((t & 63) == 0) { sh_s[wave] = s; sh_ss[wave] = ss; }
    __syncthreads();
    float S  = sh_s[0] + sh_s[1] + sh_s[2] + sh_s[3];
    float SS = sh_ss[0] + sh_ss[1] + sh_ss[2] + sh_ss[3];

    float mu  = S * (1.0f / HIDDEN);
    float var = SS * (1.0f / HIDDEN) - mu * mu;
    float inv = rsqrtf(var + LN_EPS);

    float* o = out + (long)row * HIDDEN;
#pragma unroll
    for (int i = 0; i < 3; i++) {
        int c = t + 256 * i;
        o[c] = (x[i] - mu) * inv * gamma[c] + beta[c];
    }
}

// ---------------------------------------------------------------------------
extern "C" void kernel_launch(void* const* d_in, const int* in_sizes, int n_in,
                              void* d_out, int out_size, void* d_ws, size_t ws_size,
                              hipStream_t stream)
{
    const float* query = (const float*)d_in[0];
    const float* key   = (const float*)d_in[1];
    const float* value = (const float*)d_in[2];
    const float* amask = (const float*)d_in[3];
    const float* Wq    = (const float*)d_in[5];
    const float* bq    = (const float*)d_in[6];
    const float* Wk    = (const float*)d_in[7];
    const float* bk    = (const float*)d_in[8];
    const float* Wv    = (const float*)d_in[9];
    const float* bv    = (const float*)d_in[10];
    const float* Wo    = (const float*)d_in[11];
    const float* bo    = (const float*)d_in[12];
    const float* gamma = (const float*)d_in[13];
    const float* beta  = (const float*)d_in[14];

    short* qx = (short*)d_ws;              // 4096*768  query bf16
    short* kx = qx + (long)4096 * 768;     // 8192*768  key bf16
    short* vx = kx + (long)8192 * 768;     // 8192*768  value bf16
    short* wq = vx + (long)8192 * 768;     // 768*768 x4 weights
    short* wk = wq + (long)768 * 768;
    short* wv = wk + (long)768 * 768;
    short* wo = wv + (long)768 * 768;
    short* qb = wo + (long)768 * 768;      // 4096*768  Q proj
    short* kb = qb + (long)4096 * 768;     // 8192*768  K proj
    short* vb = kb + (long)8192 * 768;     // 8192*768  V proj
    short* ctxb = qx;                      // reuse: qx dead after Q proj
    short* vt   = kx;                      // reuse: kx dead after K proj
    float* hbuf = (float*)vx;              // reuse: vx dead after V proj

    float* out0  = (float*)d_out;
    float* probs = out0 + (long)NB * LQ * HIDDEN;

    cvt_f32_bf16<<<(4096 * 768 / 4 + 255) / 256, 256, 0, stream>>>(query, qx, 4096 * 768 / 4);
    cvt_f32_bf16<<<(8192 * 768 / 4 + 255) / 256, 256, 0, stream>>>(key,   kx, 8192 * 768 / 4);
    cvt_f32_bf16<<<(8192 * 768 / 4 + 255) / 256, 256, 0, stream>>>(value, vx, 8192 * 768 / 4);
    cvt_f32_bf16<<<(768 * 768 / 4 + 255) / 256, 256, 0, stream>>>(Wq, wq, 768 * 768 / 4);
    cvt_f32_bf16<<<(768 * 768 / 4 + 255) / 256, 256, 0, stream>>>(Wk, wk, 768 * 768 / 4);
    cvt_f32_bf16<<<(768 * 768 / 4 + 255) / 256, 256, 0, stream>>>(Wv, wv, 768 * 768 / 4);
    cvt_f32_bf16<<<(768 * 768 / 4 + 255) / 256, 256, 0, stream>>>(Wo, wo, 768 * 768 / 4);

    gemm_nt_mfma<<<dim3(6, 32), 256, 0, stream>>>(
        qx, wq, nullptr, qb, bq, nullptr, HIDDEN, HIDDEN, HIDDEN, HIDDEN, 1.0f);
    gemm_nt_mfma<<<dim3(6, 64), 256, 0, stream>>>(
        kx, wk, nullptr, kb, bk, nullptr, HIDDEN, HIDDEN, HIDDEN, HIDDEN, 1.0f);
    gemm_nt_mfma<<<dim3(6, 64), 256, 0, stream>>>(
        vx, wv, nullptr, vb, bv, nullptr, HIDDEN, HIDDEN, HIDDEN, HIDDEN, 1.0f);

    transpose_v<<<dim3(4, 96), 256, 0, stream>>>(vb, vt);

    fused_attn<<<dim3(32, 96), 256, 0, stream>>>(qb, kb, vt, amask, probs, ctxb);

    gemm_nt_mfma<<<dim3(6, 32), 256, 0, stream>>>(
        ctxb, wo, hbuf, nullptr, bo, query, HIDDEN, HIDDEN, HIDDEN, HIDDEN, 1.0f);

    layernorm_rows<<<NB * LQ, 256, 0, stream>>>(hbuf, gamma, beta, out0);
}

// Round 6
// 476.471 us; speedup vs baseline: 1.2078x; 1.2078x over previous
//
#include <hip/hip_runtime.h>
#include <math.h>

#define HIDDEN 768
#define NHEADS 12
#define DHEAD  64
#define NB     8
#define LQ     512
#define LK     1024
#define LN_EPS 1e-12f
#define TS     1032   // bf16 shorts per S row (1024+8): stride 2064 B = 129 x 16B units

typedef __attribute__((ext_vector_type(8))) short short8;
typedef __attribute__((ext_vector_type(4))) float floatx4;

#define GLDS16(gp, lp) __builtin_amdgcn_global_load_lds( \
    (const __attribute__((address_space(1))) void*)(gp), \
    (__attribute__((address_space(3))) void*)(lp), 16, 0, 0)

__device__ __forceinline__ short f2bf(float f) {
    unsigned u = __float_as_uint(f);
    u = u + 0x7FFFu + ((u >> 16) & 1u);   // RNE
    return (short)(u >> 16);
}

__device__ __forceinline__ float bf2f(short s) {
    return __uint_as_float(((unsigned)(unsigned short)s) << 16);
}

// ---------------------------------------------------------------------------
// fp32 -> bf16 elementwise convert (n4 = n/4)
// ---------------------------------------------------------------------------
__global__ __launch_bounds__(256)
void cvt_f32_bf16(const float* __restrict__ in, short* __restrict__ out, int n4)
{
    int i = blockIdx.x * 256 + threadIdx.x;
    if (i >= n4) return;
    float4 v = ((const float4*)in)[i];
    short4 o;
    o.x = f2bf(v.x); o.y = f2bf(v.y); o.z = f2bf(v.z); o.w = f2bf(v.w);
    ((short4*)out)[i] = o;
}

// ---------------------------------------------------------------------------
// bf16 NT MFMA GEMM (128x128 tile, BK=32) - unchanged.
// ---------------------------------------------------------------------------
__global__ __launch_bounds__(256)
void gemm_nt_mfma(const short* __restrict__ A, const short* __restrict__ B,
                  float* __restrict__ Cf, short* __restrict__ Cb,
                  const float* __restrict__ bias, const float* __restrict__ res,
                  int K, int lda, int ldb, int ldc, float alpha)
{
    __shared__ short As[4096];
    __shared__ short Bs[4096];

    int n0 = blockIdx.x * 128;
    int m0 = blockIdx.y * 128;
    int t    = threadIdx.x;
    int lane = t & 63, wave = t >> 6;
    int quad = lane >> 4, l15 = lane & 15;
    int wr = wave >> 1, wc = wave & 1;

    int e0 = t, e1 = 256 + t;
    int r0 = e0 >> 2, c0 = (e0 & 3) ^ ((r0 >> 1) & 3);
    int r1 = e1 >> 2, c1 = (e1 & 3) ^ ((r1 >> 1) & 3);
    const short* Ap0 = A + (size_t)(m0 + r0) * lda + c0 * 8;
    const short* Ap1 = A + (size_t)(m0 + r1) * lda + c1 * 8;
    const short* Bp0 = B + (size_t)(n0 + r0) * ldb + c0 * 8;
    const short* Bp1 = B + (size_t)(n0 + r1) * ldb + c1 * 8;

    int aoff[4], boff[4];
#pragma unroll
    for (int i = 0; i < 4; i++) {
        int ra = wr * 64 + i * 16 + l15;
        aoff[i] = (ra * 4 + (quad ^ ((ra >> 1) & 3))) * 8;
        int rb = wc * 64 + i * 16 + l15;
        boff[i] = (rb * 4 + (quad ^ ((rb >> 1) & 3))) * 8;
    }

    floatx4 acc[4][4] = {};

    for (int k0 = 0; k0 < K; k0 += 32) {
        GLDS16(Ap0, &As[e0 * 8]);
        GLDS16(Ap1, &As[e1 * 8]);
        GLDS16(Bp0, &Bs[e0 * 8]);
        GLDS16(Bp1, &Bs[e1 * 8]);
        Ap0 += 32; Ap1 += 32; Bp0 += 32; Bp1 += 32;
        __syncthreads();

        short8 af[4], bfr[4];
#pragma unroll
        for (int i = 0; i < 4; i++) af[i]  = *(const short8*)&As[aoff[i]];
#pragma unroll
        for (int j = 0; j < 4; j++) bfr[j] = *(const short8*)&Bs[boff[j]];
#pragma unroll
        for (int i = 0; i < 4; i++)
#pragma unroll
            for (int j = 0; j < 4; j++)
                acc[i][j] = __builtin_amdgcn_mfma_f32_16x16x32_bf16(
                    af[i], bfr[j], acc[i][j], 0, 0, 0);
        __syncthreads();
    }

#pragma unroll
    for (int i = 0; i < 4; i++) {
        int mb = m0 + wr * 64 + i * 16 + quad * 4;
#pragma unroll
        for (int j = 0; j < 4; j++) {
            int n = n0 + wc * 64 + j * 16 + l15;
            float bv = bias ? bias[n] : 0.f;
#pragma unroll
            for (int r = 0; r < 4; r++) {
                int m = mb + r;
                float v = alpha * acc[i][j][r] + bv;
                if (res) v += res[(size_t)m * ldc + n];
                if (Cb) Cb[(size_t)m * ldc + n] = f2bf(v);
                else    Cf[(size_t)m * ldc + n] = v;
            }
        }
    }
}

// ---------------------------------------------------------------------------
// Transpose V proj: vb [B, LK, 768] -> vt [bh][64 d][1024 k]
// ---------------------------------------------------------------------------
__global__ __launch_bounds__(256)
void transpose_v(const short* __restrict__ vb, short* __restrict__ vt)
{
    __shared__ short T[256 * 72];   // 36 KB, pad 72 to break bank conflicts
    int kt = blockIdx.x, bh = blockIdx.y;
    int b = bh / 12, h = bh - b * 12;
    int t = threadIdx.x;
    const short* src = vb + ((size_t)b * LK + kt * 256) * HIDDEN + h * DHEAD;
#pragma unroll
    for (int it = 0; it < 8; it++) {
        int s = it * 256 + t;
        int k = s >> 3, c = s & 7;
        *(short8*)&T[k * 72 + c * 8] =
            *(const short8*)&src[(size_t)k * HIDDEN + c * 8];
    }
    __syncthreads();
    short* dst = vt + (size_t)bh * DHEAD * LK + kt * 256;
#pragma unroll
    for (int it = 0; it < 8; it++) {
        int s = it * 256 + t;
        int d = s >> 5, kc = s & 31;
        short8 v;
#pragma unroll
        for (int i = 0; i < 8; i++) v[i] = T[(kc * 8 + i) * 72 + d];
        *(short8*)&dst[(size_t)d * LK + kc * 8] = v;
    }
}

// ---------------------------------------------------------------------------
// Fused attention v3 (resubmit #2; R3/R5 were infra failures, R4 verified
// everything except the floatx4 nontemporal-store form):
//  - S: 16 x 1032 bf16 = 33 KB; KV staging 16 KB -> ~49.7 KB -> 3 blocks/CU
//  - K/V staged via global_load_lds (1KB coalesced), single buffer,
//    stage-after-use with epilogue/probs-emit overlapping the flight (R0)
//  - probs written with __builtin_nontemporal_store: the 201 MB stream no
//    longer evicts K/V from L2 (round-2 FETCH was 81 MB vs ~31 ideal)
//  - scores pre-scaled by log2(e); exp2f replaces expf (saves 64 muls/thread)
// ---------------------------------------------------------------------------
__global__ __launch_bounds__(256)
void fused_attn(const short* __restrict__ qb, const short* __restrict__ kb,
                const short* __restrict__ vt, const float* __restrict__ amask,
                float* __restrict__ probs, short* __restrict__ ctxb)
{
    __shared__ short S[16 * TS];           // 33 KB bf16 scores -> exp2'd
    __shared__ short KV[8192];             // 16 KB K/V chunk staging
    __shared__ float mpart[4][16];
    __shared__ float lrow[16];

    // XCD remap: consecutive flat ids round-robin XCDs (xcd = flat & 7).
    int flat = blockIdx.y * 32 + blockIdx.x;       // 0..3071
    int jj   = flat >> 3;                          // 0..383
    int bh   = (flat & 7) * 12 + jj % 12;
    int qt   = jj / 12;                            // 0..31
    int b = bh / 12, h = bh - b * 12;
    int m0 = qt * 16;

    const short* Qg = qb + ((size_t)b * LQ + m0) * HIDDEN + h * DHEAD;
    const short* Kg = kb + (size_t)b * LK * HIDDEN + h * DHEAD;
    const short* Vg = vt + (size_t)bh * DHEAD * LK;
    const float* Mg = amask + (size_t)b * LK;
    float* Pg = probs + (size_t)bh * LQ * LK + (size_t)m0 * LK;
    short* Cg = ctxb + ((size_t)b * LQ + m0) * HIDDEN + h * DHEAD;

    int t = threadIdx.x;
    int lane = t & 63, w = t >> 6;
    int quad = lane >> 4, l15 = lane & 15;

    // stage K chunk 0 (128 rows x 64 cols bf16, XOR-swizzled source)
#pragma unroll
    for (int I = 0; I < 4; I++) {
        int s = I * 256 + t;
        int r = s >> 3, cs = s & 7, c = cs ^ (r & 7);
        GLDS16(Kg + (size_t)r * HIDDEN + c * 8, &KV[s * 8]);
    }

    // Q fragments straight from global (2 KB/block, L2-resident)
    short8 af[2];
#pragma unroll
    for (int ks = 0; ks < 2; ks++)
        af[ks] = *(const short8*)&Qg[(size_t)l15 * HIDDEN + ks * 32 + quad * 8];

    float mx[4];
#pragma unroll
    for (int r = 0; r < 4; r++) mx[r] = -3.0e38f;

    const float SC  = 0.125f * 1.44269504089f;   // (1/sqrt(64)) * log2(e)
    const float L2E = 1.44269504089f;

    // ====== scores: 8 chunks of 128 K rows; stage-after-use pipeline ======
    for (int kc = 0; kc < 8; kc++) {
        __syncthreads();            // chunk kc resident in KV
        floatx4 acc[2] = {};
#pragma unroll
        for (int ks = 0; ks < 2; ks++)
#pragma unroll
            for (int j = 0; j < 2; j++) {
                int rK = w * 32 + j * 16 + l15;
                int cs = (ks * 4 + quad) ^ (rK & 7);
                short8 bfr = *(const short8*)&KV[(rK * 8 + cs) * 8];
                acc[j] = __builtin_amdgcn_mfma_f32_16x16x32_bf16(
                    af[ks], bfr, acc[j], 0, 0, 0);
            }
        __syncthreads();            // all KV reads complete
        if (kc < 7) {               // stage next chunk; flight hides epilogue
            const short* Kn = Kg + (size_t)(kc + 1) * 128 * HIDDEN;
#pragma unroll
            for (int I = 0; I < 4; I++) {
                int s = I * 256 + t;
                int r = s >> 3, cs = s & 7, c = cs ^ (r & 7);
                GLDS16(Kn + (size_t)r * HIDDEN + c * 8, &KV[s * 8]);
            }
        }
        // epilogue: scaled scores -> S (bf16), track row max
#pragma unroll
        for (int j = 0; j < 2; j++) {
            int n = kc * 128 + w * 32 + j * 16 + l15;
            float mk = Mg[n] * L2E;
#pragma unroll
            for (int r = 0; r < 4; r++) {
                int m = quad * 4 + r;
                float v = acc[j][r] * SC + mk;
                S[m * TS + n] = f2bf(v);
                mx[r] = fmaxf(mx[r], v);
            }
        }
    }

    // row max: shuffle across l15 (cols within wave), mpart across waves
#pragma unroll
    for (int d = 1; d < 16; d <<= 1)
#pragma unroll
        for (int r = 0; r < 4; r++)
            mx[r] = fmaxf(mx[r], __shfl_xor(mx[r], d));
    if (l15 == 0)
#pragma unroll
        for (int r = 0; r < 4; r++)
            mpart[w][quad * 4 + r] = mx[r];
    __syncthreads();                // mpart + all S writes visible

    // stage V chunk 0 (64 d-rows x 128 k, swizzled); flight hides exp phase
#pragma unroll
    for (int I = 0; I < 4; I++) {
        int s = I * 256 + t;
        int n = s >> 4, cs = s & 15, c = cs ^ (n & 15);
        GLDS16(Vg + (size_t)n * LK + c * 8, &KV[s * 8]);
    }

    // exp2 in place (bf16) + row sums; 16 lanes per row
    {
        int r = t >> 4, seg = t & 15;
        float mr = fmaxf(fmaxf(mpart[0][r], mpart[1][r]),
                         fmaxf(mpart[2][r], mpart[3][r]));
        float sum = 0.f;
#pragma unroll
        for (int i = 0; i < 8; i++) {
            int u = i * 16 + seg;
            short8 v = *(const short8*)&S[r * TS + u * 8];
            short8 o;
#pragma unroll
            for (int e = 0; e < 8; e++) {
                float f = exp2f(bf2f(v[e]) - mr);
                o[e] = f2bf(f);
                sum += f;
            }
            *(short8*)&S[r * TS + u * 8] = o;
        }
        sum += __shfl_xor(sum, 1);
        sum += __shfl_xor(sum, 2);
        sum += __shfl_xor(sum, 4);
        sum += __shfl_xor(sum, 8);
        if (seg == 0) lrow[r] = sum;
    }

    // ====== PV + probs emission merged: 8 chunks of 128 k =================
    floatx4 accO = {};
    for (int kc = 0; kc < 8; kc++) {
        __syncthreads();            // V chunk kc resident (kc=0: + S/lrow)
#pragma unroll
        for (int ks = 0; ks < 4; ks++) {
            short8 pa = *(const short8*)&S[l15 * TS + kc * 128
                                           + ks * 32 + quad * 8];
            int n = w * 16 + l15;
            int cs = (ks * 4 + quad) ^ (n & 15);
            short8 bfr = *(const short8*)&KV[(n * 16 + cs) * 8];
            accO = __builtin_amdgcn_mfma_f32_16x16x32_bf16(
                pa, bfr, accO, 0, 0, 0);
        }
        __syncthreads();            // all KV reads complete
        if (kc < 7) {               // stage next V chunk
            const short* Vn = Vg + (kc + 1) * 128;
#pragma unroll
            for (int I = 0; I < 4; I++) {
                int s = I * 256 + t;
                int n = s >> 4, cs = s & 15, c = cs ^ (n & 15);
                GLDS16(Vn + (size_t)n * LK + c * 8, &KV[s * 8]);
            }
        }
        // emit 2 probs rows (nontemporal; overlaps staging flight + MFMA)
#pragma unroll
        for (int rr = 0; rr < 2; rr++) {
            int r = kc * 2 + rr;
            float inv = 1.0f / lrow[r];
            short4 v = *(const short4*)&S[r * TS + t * 4];
            floatx4 o;
            o.x = bf2f(v.x) * inv; o.y = bf2f(v.y) * inv;
            o.z = bf2f(v.z) * inv; o.w = bf2f(v.w) * inv;
            __builtin_nontemporal_store(
                o, (floatx4*)(Pg + (size_t)r * LK) + t);
        }
    }

    // ctx epilogue: rescale by 1/l, bf16 out
    int n = w * 16 + l15;
#pragma unroll
    for (int r = 0; r < 4; r++) {
        int m = quad * 4 + r;
        Cg[(size_t)m * HIDDEN + n] = f2bf(accO[r] / lrow[m]);
    }
}

// ---------------------------------------------------------------------------
// Row LayerNorm over HIDDEN=768; one block per row.
// ---------------------------------------------------------------------------
__global__ __launch_bounds__(256)
void layernorm_rows(const float* __restrict__ H, const float* __restrict__ gamma,
                    const float* __restrict__ beta, float* __restrict__ out)
{
    int row = blockIdx.x;
    const float* h = H + (long)row * HIDDEN;
    int t = threadIdx.x;

    float x[3];
    float s = 0.f, ss = 0.f;
#pragma unroll
    for (int i = 0; i < 3; i++) {
        x[i] = h[t + 256 * i];
        s  += x[i];
        ss += x[i] * x[i];
    }
#pragma unroll
    for (int off = 32; off > 0; off >>= 1) {
        s  += __shfl_down(s, off);
        ss += __shfl_down(ss, off);
    }
    __shared__ float sh_s[4], sh_ss[4];
    int wave = t >> 6;
    if ((t & 63) == 0) { sh_s[wave] = s; sh_ss[wave] = ss; }
    __syncthreads();
    float S  = sh_s[0] + sh_s[1] + sh_s[2] + sh_s[3];
    float SS = sh_ss[0] + sh_ss[1] + sh_ss[2] + sh_ss[3];

    float mu  = S * (1.0f / HIDDEN);
    float var = SS * (1.0f / HIDDEN) - mu * mu;
    float inv = rsqrtf(var + LN_EPS);

    float* o = out + (long)row * HIDDEN;
#pragma unroll
    for (int i = 0; i < 3; i++) {
        int c = t + 256 * i;
        o[c] = (x[i] - mu) * inv * gamma[c] + beta[c];
    }
}

// ---------------------------------------------------------------------------
extern "C" void kernel_launch(void* const* d_in, const int* in_sizes, int n_in,
                              void* d_out, int out_size, void* d_ws, size_t ws_size,
                              hipStream_t stream)
{
    const float* query = (const float*)d_in[0];
    const float* key   = (const float*)d_in[1];
    const float* value = (const float*)d_in[2];
    const float* amask = (const float*)d_in[3];
    const float* Wq    = (const float*)d_in[5];
    const float* bq    = (const float*)d_in[6];
    const float* Wk    = (const float*)d_in[7];
    const float* bk    = (const float*)d_in[8];
    const float* Wv    = (const float*)d_in[9];
    const float* bv    = (const float*)d_in[10];
    const float* Wo    = (const float*)d_in[11];
    const float* bo    = (const float*)d_in[12];
    const float* gamma = (const float*)d_in[13];
    const float* beta  = (const float*)d_in[14];

    short* qx = (short*)d_ws;              // 4096*768  query bf16
    short* kx = qx + (long)4096 * 768;     // 8192*768  key bf16
    short* vx = kx + (long)8192 * 768;     // 8192*768  value bf16
    short* wq = vx + (long)8192 * 768;     // 768*768 x4 weights
    short* wk = wq + (long)768 * 768;
    short* wv = wk + (long)768 * 768;
    short* wo = wv + (long)768 * 768;
    short* qb = wo + (long)768 * 768;      // 4096*768  Q proj
    short* kb = qb + (long)4096 * 768;     // 8192*768  K proj
    short* vb = kb + (long)8192 * 768;     // 8192*768  V proj
    short* ctxb = qx;                      // reuse: qx dead after Q proj
    short* vt   = kx;                      // reuse: kx dead after K proj
    float* hbuf = (float*)vx;              // reuse: vx dead after V proj

    float* out0  = (float*)d_out;
    float* probs = out0 + (long)NB * LQ * HIDDEN;

    cvt_f32_bf16<<<(4096 * 768 / 4 + 255) / 256, 256, 0, stream>>>(query, qx, 4096 * 768 / 4);
    cvt_f32_bf16<<<(8192 * 768 / 4 + 255) / 256, 256, 0, stream>>>(key,   kx, 8192 * 768 / 4);
    cvt_f32_bf16<<<(8192 * 768 / 4 + 255) / 256, 256, 0, stream>>>(value, vx, 8192 * 768 / 4);
    cvt_f32_bf16<<<(768 * 768 / 4 + 255) / 256, 256, 0, stream>>>(Wq, wq, 768 * 768 / 4);
    cvt_f32_bf16<<<(768 * 768 / 4 + 255) / 256, 256, 0, stream>>>(Wk, wk, 768 * 768 / 4);
    cvt_f32_bf16<<<(768 * 768 / 4 + 255) / 256, 256, 0, stream>>>(Wv, wv, 768 * 768 / 4);
    cvt_f32_bf16<<<(768 * 768 / 4 + 255) / 256, 256, 0, stream>>>(Wo, wo, 768 * 768 / 4);

    gemm_nt_mfma<<<dim3(6, 32), 256, 0, stream>>>(
        qx, wq, nullptr, qb, bq, nullptr, HIDDEN, HIDDEN, HIDDEN, HIDDEN, 1.0f);
    gemm_nt_mfma<<<dim3(6, 64), 256, 0, stream>>>(
        kx, wk, nullptr, kb, bk, nullptr, HIDDEN, HIDDEN, HIDDEN, HIDDEN, 1.0f);
    gemm_nt_mfma<<<dim3(6, 64), 256, 0, stream>>>(
        vx, wv, nullptr, vb, bv, nullptr, HIDDEN, HIDDEN, HIDDEN, HIDDEN, 1.0f);

    transpose_v<<<dim3(4, 96), 256, 0, stream>>>(vb, vt);

    fused_attn<<<dim3(32, 96), 256, 0, stream>>>(qb, kb, vt, amask, probs, ctxb);

    gemm_nt_mfma<<<dim3(6, 32), 256, 0, stream>>>(
        ctxb, wo, hbuf, nullptr, bo, query, HIDDEN, HIDDEN, HIDDEN, HIDDEN, 1.0f);

    layernorm_rows<<<NB * LQ, 256, 0, stream>>>(hbuf, gamma, beta, out0);
}

// Round 7
// 436.428 us; speedup vs baseline: 1.3186x; 1.0918x over previous
//
#include <hip/hip_runtime.h>
#include <math.h>

#define HIDDEN 768
#define NHEADS 12
#define DHEAD  64
#define NB     8
#define LQ     512
#define LK     1024
#define LN_EPS 1e-12f
#define TS     1032   // bf16 shorts per S row (1024+8): stride 2064 B = 129 x 16B units

typedef __attribute__((ext_vector_type(8))) short short8;
typedef __attribute__((ext_vector_type(4))) float floatx4;

#define GLDS16(gp, lp) __builtin_amdgcn_global_load_lds( \
    (const __attribute__((address_space(1))) void*)(gp), \
    (__attribute__((address_space(3))) void*)(lp), 16, 0, 0)

__device__ __forceinline__ short f2bf(float f) {
    unsigned u = __float_as_uint(f);
    u = u + 0x7FFFu + ((u >> 16) & 1u);   // RNE
    return (short)(u >> 16);
}

__device__ __forceinline__ float bf2f(short s) {
    return __uint_as_float(((unsigned)(unsigned short)s) << 16);
}

// ---------------------------------------------------------------------------
// Fused fp32 -> bf16 convert for all 7 tensors in ONE launch.
// Segments (256 float4-units per block, all sizes exact multiples):
//   [0,3072)      query  4096x768
//   [3072,9216)   key    8192x768
//   [9216,15360)  value  8192x768
//   [15360,17664) Wq,Wk,Wv,Wo  4 x 768x768 (576 blocks each)
// ---------------------------------------------------------------------------
__global__ __launch_bounds__(256)
void cvt_all(const float* __restrict__ q, const float* __restrict__ k,
             const float* __restrict__ v,
             const float* __restrict__ Wq, const float* __restrict__ Wk,
             const float* __restrict__ Wv, const float* __restrict__ Wo,
             short* __restrict__ dq, short* __restrict__ dk,
             short* __restrict__ dv,
             short* __restrict__ dwq, short* __restrict__ dwk,
             short* __restrict__ dwv, short* __restrict__ dwo)
{
    int bx = blockIdx.x;
    const float* src; short* dst; int base;
    if (bx < 3072)       { src = q; dst = dq; base = bx; }
    else if (bx < 9216)  { src = k; dst = dk; base = bx - 3072; }
    else if (bx < 15360) { src = v; dst = dv; base = bx - 9216; }
    else {
        int wb = bx - 15360, wsel = wb / 576;
        base = wb - wsel * 576;
        src = (wsel == 0) ? Wq : (wsel == 1) ? Wk : (wsel == 2) ? Wv : Wo;
        dst = (wsel == 0) ? dwq : (wsel == 1) ? dwk : (wsel == 2) ? dwv : dwo;
    }
    int i = base * 256 + threadIdx.x;
    float4 vv = ((const float4*)src)[i];
    short4 o;
    o.x = f2bf(vv.x); o.y = f2bf(vv.y); o.z = f2bf(vv.z); o.w = f2bf(vv.w);
    ((short4*)dst)[i] = o;
}

// ---------------------------------------------------------------------------
// bf16 NT MFMA GEMM core (128x128 tile, BK=32), double-buffered LDS:
// stage(s+1) issued BEFORE compute(s), single barrier per K-step -> the
// staging flight overlaps MFMA instead of being drained immediately.
// ---------------------------------------------------------------------------
__device__ __forceinline__ void gemm_core(
    short (*As)[4096], short (*Bs)[4096],
    const short* __restrict__ A, const short* __restrict__ B,
    float* Cf, short* Cb,
    const float* bias, const float* res,
    int m0, int n0, int K, int lda, int ldb, int ldc, float alpha)
{
    int t    = threadIdx.x;
    int lane = t & 63, wave = t >> 6;
    int quad = lane >> 4, l15 = lane & 15;
    int wr = wave >> 1, wc = wave & 1;

    int e0 = t, e1 = 256 + t;
    int r0 = e0 >> 2, c0 = (e0 & 3) ^ ((r0 >> 1) & 3);
    int r1 = e1 >> 2, c1 = (e1 & 3) ^ ((r1 >> 1) & 3);
    const short* Ap0 = A + (size_t)(m0 + r0) * lda + c0 * 8;
    const short* Ap1 = A + (size_t)(m0 + r1) * lda + c1 * 8;
    const short* Bp0 = B + (size_t)(n0 + r0) * ldb + c0 * 8;
    const short* Bp1 = B + (size_t)(n0 + r1) * ldb + c1 * 8;

    int aoff[4], boff[4];
#pragma unroll
    for (int i = 0; i < 4; i++) {
        int ra = wr * 64 + i * 16 + l15;
        aoff[i] = (ra * 4 + (quad ^ ((ra >> 1) & 3))) * 8;
        int rb = wc * 64 + i * 16 + l15;
        boff[i] = (rb * 4 + (quad ^ ((rb >> 1) & 3))) * 8;
    }

    floatx4 acc[4][4] = {};
    int nsteps = K >> 5;

    // prologue: stage step 0 into buffer 0
    GLDS16(Ap0, &As[0][e0 * 8]);
    GLDS16(Ap1, &As[0][e1 * 8]);
    GLDS16(Bp0, &Bs[0][e0 * 8]);
    GLDS16(Bp1, &Bs[0][e1 * 8]);
    Ap0 += 32; Ap1 += 32; Bp0 += 32; Bp1 += 32;

    for (int s = 0; s < nsteps; s++) {
        int cur = s & 1;
        __syncthreads();            // buf[cur] staged; buf[cur^1] reads done
        if (s + 1 < nsteps) {       // stage next; flight overlaps compute
            GLDS16(Ap0, &As[cur ^ 1][e0 * 8]);
            GLDS16(Ap1, &As[cur ^ 1][e1 * 8]);
            GLDS16(Bp0, &Bs[cur ^ 1][e0 * 8]);
            GLDS16(Bp1, &Bs[cur ^ 1][e1 * 8]);
            Ap0 += 32; Ap1 += 32; Bp0 += 32; Bp1 += 32;
        }
        short8 af[4], bfr[4];
#pragma unroll
        for (int i = 0; i < 4; i++) af[i]  = *(const short8*)&As[cur][aoff[i]];
#pragma unroll
        for (int j = 0; j < 4; j++) bfr[j] = *(const short8*)&Bs[cur][boff[j]];
#pragma unroll
        for (int i = 0; i < 4; i++)
#pragma unroll
            for (int j = 0; j < 4; j++)
                acc[i][j] = __builtin_amdgcn_mfma_f32_16x16x32_bf16(
                    af[i], bfr[j], acc[i][j], 0, 0, 0);
    }

#pragma unroll
    for (int i = 0; i < 4; i++) {
        int mb = m0 + wr * 64 + i * 16 + quad * 4;
#pragma unroll
        for (int j = 0; j < 4; j++) {
            int n = n0 + wc * 64 + j * 16 + l15;
            float bv = bias ? bias[n] : 0.f;
#pragma unroll
            for (int r = 0; r < 4; r++) {
                int m = mb + r;
                float v = alpha * acc[i][j][r] + bv;
                if (res) v += res[(size_t)m * ldc + n];
                if (Cb) Cb[(size_t)m * ldc + n] = f2bf(v);
                else    Cf[(size_t)m * ldc + n] = v;
            }
        }
    }
}

__global__ __launch_bounds__(256)
void gemm_nt_mfma(const short* __restrict__ A, const short* __restrict__ B,
                  float* __restrict__ Cf, short* __restrict__ Cb,
                  const float* __restrict__ bias, const float* __restrict__ res,
                  int K, int lda, int ldb, int ldc, float alpha)
{
    __shared__ short As[2][4096];
    __shared__ short Bs[2][4096];
    gemm_core(As, Bs, A, B, Cf, Cb, bias, res,
              blockIdx.y * 128, blockIdx.x * 128, K, lda, ldb, ldc, alpha);
}

// Q/K/V projections fused into one launch: blockIdx.y selects matrix.
//   y in [0,32)   -> Q rows (4096)
//   y in [32,96)  -> K rows (8192)
//   y in [96,160) -> V rows (8192)
__global__ __launch_bounds__(256)
void qkv_gemm(const short* __restrict__ qx, const short* __restrict__ kx,
              const short* __restrict__ vx,
              const short* __restrict__ wq, const short* __restrict__ wk,
              const short* __restrict__ wv,
              const float* __restrict__ bq, const float* __restrict__ bk,
              const float* __restrict__ bv,
              short* __restrict__ qb, short* __restrict__ kb,
              short* __restrict__ vb)
{
    __shared__ short As[2][4096];
    __shared__ short Bs[2][4096];
    int yb = blockIdx.y;
    const short *A, *B; const float* bias; short* C; int m0;
    if (yb < 32)      { A = qx; B = wq; bias = bq; C = qb; m0 = yb * 128; }
    else if (yb < 96) { A = kx; B = wk; bias = bk; C = kb; m0 = (yb - 32) * 128; }
    else              { A = vx; B = wv; bias = bv; C = vb; m0 = (yb - 96) * 128; }
    gemm_core(As, Bs, A, B, nullptr, C, bias, nullptr,
              m0, blockIdx.x * 128, HIDDEN, HIDDEN, HIDDEN, HIDDEN, 1.0f);
}

// ---------------------------------------------------------------------------
// Transpose V proj: vb [B, LK, 768] -> vt [bh][64 d][1024 k]
// ---------------------------------------------------------------------------
__global__ __launch_bounds__(256)
void transpose_v(const short* __restrict__ vb, short* __restrict__ vt)
{
    __shared__ short T[256 * 72];   // 36 KB, pad 72 to break bank conflicts
    int kt = blockIdx.x, bh = blockIdx.y;
    int b = bh / 12, h = bh - b * 12;
    int t = threadIdx.x;
    const short* src = vb + ((size_t)b * LK + kt * 256) * HIDDEN + h * DHEAD;
#pragma unroll
    for (int it = 0; it < 8; it++) {
        int s = it * 256 + t;
        int k = s >> 3, c = s & 7;
        *(short8*)&T[k * 72 + c * 8] =
            *(const short8*)&src[(size_t)k * HIDDEN + c * 8];
    }
    __syncthreads();
    short* dst = vt + (size_t)bh * DHEAD * LK + kt * 256;
#pragma unroll
    for (int it = 0; it < 8; it++) {
        int s = it * 256 + t;
        int d = s >> 5, kc = s & 31;
        short8 v;
#pragma unroll
        for (int i = 0; i < 8; i++) v[i] = T[(kc * 8 + i) * 72 + d];
        *(short8*)&dst[(size_t)d * LK + kc * 8] = v;
    }
}

// ---------------------------------------------------------------------------
// Fused attention (unchanged from the round-6 win):
//  - S: 16 x 1032 bf16 = 33 KB; KV staging 16 KB -> ~49.7 KB -> 3 blocks/CU
//  - K/V staged via global_load_lds, single buffer, stage-after-use
//  - probs written with __builtin_nontemporal_store (no L2 eviction of K/V)
//  - scores pre-scaled by log2(e); exp2f
// ---------------------------------------------------------------------------
__global__ __launch_bounds__(256)
void fused_attn(const short* __restrict__ qb, const short* __restrict__ kb,
                const short* __restrict__ vt, const float* __restrict__ amask,
                float* __restrict__ probs, short* __restrict__ ctxb)
{
    __shared__ short S[16 * TS];           // 33 KB bf16 scores -> exp2'd
    __shared__ short KV[8192];             // 16 KB K/V chunk staging
    __shared__ float mpart[4][16];
    __shared__ float lrow[16];

    // XCD remap: consecutive flat ids round-robin XCDs (xcd = flat & 7).
    int flat = blockIdx.y * 32 + blockIdx.x;       // 0..3071
    int jj   = flat >> 3;                          // 0..383
    int bh   = (flat & 7) * 12 + jj % 12;
    int qt   = jj / 12;                            // 0..31
    int b = bh / 12, h = bh - b * 12;
    int m0 = qt * 16;

    const short* Qg = qb + ((size_t)b * LQ + m0) * HIDDEN + h * DHEAD;
    const short* Kg = kb + (size_t)b * LK * HIDDEN + h * DHEAD;
    const short* Vg = vt + (size_t)bh * DHEAD * LK;
    const float* Mg = amask + (size_t)b * LK;
    float* Pg = probs + (size_t)bh * LQ * LK + (size_t)m0 * LK;
    short* Cg = ctxb + ((size_t)b * LQ + m0) * HIDDEN + h * DHEAD;

    int t = threadIdx.x;
    int lane = t & 63, w = t >> 6;
    int quad = lane >> 4, l15 = lane & 15;

    // stage K chunk 0 (128 rows x 64 cols bf16, XOR-swizzled source)
#pragma unroll
    for (int I = 0; I < 4; I++) {
        int s = I * 256 + t;
        int r = s >> 3, cs = s & 7, c = cs ^ (r & 7);
        GLDS16(Kg + (size_t)r * HIDDEN + c * 8, &KV[s * 8]);
    }

    // Q fragments straight from global (2 KB/block, L2-resident)
    short8 af[2];
#pragma unroll
    for (int ks = 0; ks < 2; ks++)
        af[ks] = *(const short8*)&Qg[(size_t)l15 * HIDDEN + ks * 32 + quad * 8];

    float mx[4];
#pragma unroll
    for (int r = 0; r < 4; r++) mx[r] = -3.0e38f;

    const float SC  = 0.125f * 1.44269504089f;   // (1/sqrt(64)) * log2(e)
    const float L2E = 1.44269504089f;

    // ====== scores: 8 chunks of 128 K rows; stage-after-use pipeline ======
    for (int kc = 0; kc < 8; kc++) {
        __syncthreads();            // chunk kc resident in KV
        floatx4 acc[2] = {};
#pragma unroll
        for (int ks = 0; ks < 2; ks++)
#pragma unroll
            for (int j = 0; j < 2; j++) {
                int rK = w * 32 + j * 16 + l15;
                int cs = (ks * 4 + quad) ^ (rK & 7);
                short8 bfr = *(const short8*)&KV[(rK * 8 + cs) * 8];
                acc[j] = __builtin_amdgcn_mfma_f32_16x16x32_bf16(
                    af[ks], bfr, acc[j], 0, 0, 0);
            }
        __syncthreads();            // all KV reads complete
        if (kc < 7) {               // stage next chunk; flight hides epilogue
            const short* Kn = Kg + (size_t)(kc + 1) * 128 * HIDDEN;
#pragma unroll
            for (int I = 0; I < 4; I++) {
                int s = I * 256 + t;
                int r = s >> 3, cs = s & 7, c = cs ^ (r & 7);
                GLDS16(Kn + (size_t)r * HIDDEN + c * 8, &KV[s * 8]);
            }
        }
        // epilogue: scaled scores -> S (bf16), track row max
#pragma unroll
        for (int j = 0; j < 2; j++) {
            int n = kc * 128 + w * 32 + j * 16 + l15;
            float mk = Mg[n] * L2E;
#pragma unroll
            for (int r = 0; r < 4; r++) {
                int m = quad * 4 + r;
                float v = acc[j][r] * SC + mk;
                S[m * TS + n] = f2bf(v);
                mx[r] = fmaxf(mx[r], v);
            }
        }
    }

    // row max: shuffle across l15 (cols within wave), mpart across waves
#pragma unroll
    for (int d = 1; d < 16; d <<= 1)
#pragma unroll
        for (int r = 0; r < 4; r++)
            mx[r] = fmaxf(mx[r], __shfl_xor(mx[r], d));
    if (l15 == 0)
#pragma unroll
        for (int r = 0; r < 4; r++)
            mpart[w][quad * 4 + r] = mx[r];
    __syncthreads();                // mpart + all S writes visible

    // stage V chunk 0 (64 d-rows x 128 k, swizzled); flight hides exp phase
#pragma unroll
    for (int I = 0; I < 4; I++) {
        int s = I * 256 + t;
        int n = s >> 4, cs = s & 15, c = cs ^ (n & 15);
        GLDS16(Vg + (size_t)n * LK + c * 8, &KV[s * 8]);
    }

    // exp2 in place (bf16) + row sums; 16 lanes per row
    {
        int r = t >> 4, seg = t & 15;
        float mr = fmaxf(fmaxf(mpart[0][r], mpart[1][r]),
                         fmaxf(mpart[2][r], mpart[3][r]));
        float sum = 0.f;
#pragma unroll
        for (int i = 0; i < 8; i++) {
            int u = i * 16 + seg;
            short8 v = *(const short8*)&S[r * TS + u * 8];
            short8 o;
#pragma unroll
            for (int e = 0; e < 8; e++) {
                float f = exp2f(bf2f(v[e]) - mr);
                o[e] = f2bf(f);
                sum += f;
            }
            *(short8*)&S[r * TS + u * 8] = o;
        }
        sum += __shfl_xor(sum, 1);
        sum += __shfl_xor(sum, 2);
        sum += __shfl_xor(sum, 4);
        sum += __shfl_xor(sum, 8);
        if (seg == 0) lrow[r] = sum;
    }

    // ====== PV + probs emission merged: 8 chunks of 128 k =================
    floatx4 accO = {};
    for (int kc = 0; kc < 8; kc++) {
        __syncthreads();            // V chunk kc resident (kc=0: + S/lrow)
#pragma unroll
        for (int ks = 0; ks < 4; ks++) {
            short8 pa = *(const short8*)&S[l15 * TS + kc * 128
                                           + ks * 32 + quad * 8];
            int n = w * 16 + l15;
            int cs = (ks * 4 + quad) ^ (n & 15);
            short8 bfr = *(const short8*)&KV[(n * 16 + cs) * 8];
            accO = __builtin_amdgcn_mfma_f32_16x16x32_bf16(
                pa, bfr, accO, 0, 0, 0);
        }
        __syncthreads();            // all KV reads complete
        if (kc < 7) {               // stage next V chunk
            const short* Vn = Vg + (kc + 1) * 128;
#pragma unroll
            for (int I = 0; I < 4; I++) {
                int s = I * 256 + t;
                int n = s >> 4, cs = s & 15, c = cs ^ (n & 15);
                GLDS16(Vn + (size_t)n * LK + c * 8, &KV[s * 8]);
            }
        }
        // emit 2 probs rows (nontemporal; overlaps staging flight + MFMA)
#pragma unroll
        for (int rr = 0; rr < 2; rr++) {
            int r = kc * 2 + rr;
            float inv = 1.0f / lrow[r];
            short4 v = *(const short4*)&S[r * TS + t * 4];
            floatx4 o;
            o.x = bf2f(v.x) * inv; o.y = bf2f(v.y) * inv;
            o.z = bf2f(v.z) * inv; o.w = bf2f(v.w) * inv;
            __builtin_nontemporal_store(
                o, (floatx4*)(Pg + (size_t)r * LK) + t);
        }
    }

    // ctx epilogue: rescale by 1/l, bf16 out
    int n = w * 16 + l15;
#pragma unroll
    for (int r = 0; r < 4; r++) {
        int m = quad * 4 + r;
        Cg[(size_t)m * HIDDEN + n] = f2bf(accO[r] / lrow[m]);
    }
}

// ---------------------------------------------------------------------------
// Row LayerNorm over HIDDEN=768; one block per row.
// ---------------------------------------------------------------------------
__global__ __launch_bounds__(256)
void layernorm_rows(const float* __restrict__ H, const float* __restrict__ gamma,
                    const float* __restrict__ beta, float* __restrict__ out)
{
    int row = blockIdx.x;
    const float* h = H + (long)row * HIDDEN;
    int t = threadIdx.x;

    float x[3];
    float s = 0.f, ss = 0.f;
#pragma unroll
    for (int i = 0; i < 3; i++) {
        x[i] = h[t + 256 * i];
        s  += x[i];
        ss += x[i] * x[i];
    }
#pragma unroll
    for (int off = 32; off > 0; off >>= 1) {
        s  += __shfl_down(s, off);
        ss += __shfl_down(ss, off);
    }
    __shared__ float sh_s[4], sh_ss[4];
    int wave = t >> 6;
    if ((t & 63) == 0) { sh_s[wave] = s; sh_ss[wave] = ss; }
    __syncthreads();
    float S  = sh_s[0] + sh_s[1] + sh_s[2] + sh_s[3];
    float SS = sh_ss[0] + sh_ss[1] + sh_ss[2] + sh_ss[3];

    float mu  = S * (1.0f / HIDDEN);
    float var = SS * (1.0f / HIDDEN) - mu * mu;
    float inv = rsqrtf(var + LN_EPS);

    float* o = out + (long)row * HIDDEN;
#pragma unroll
    for (int i = 0; i < 3; i++) {
        int c = t + 256 * i;
        o[c] = (x[i] - mu) * inv * gamma[c] + beta[c];
    }
}

// ---------------------------------------------------------------------------
extern "C" void kernel_launch(void* const* d_in, const int* in_sizes, int n_in,
                              void* d_out, int out_size, void* d_ws, size_t ws_size,
                              hipStream_t stream)
{
    const float* query = (const float*)d_in[0];
    const float* key   = (const float*)d_in[1];
    const float* value = (const float*)d_in[2];
    const float* amask = (const float*)d_in[3];
    const float* Wq    = (const float*)d_in[5];
    const float* bq    = (const float*)d_in[6];
    const float* Wk    = (const float*)d_in[7];
    const float* bk    = (const float*)d_in[8];
    const float* Wv    = (const float*)d_in[9];
    const float* bv    = (const float*)d_in[10];
    const float* Wo    = (const float*)d_in[11];
    const float* bo    = (const float*)d_in[12];
    const float* gamma = (const float*)d_in[13];
    const float* beta  = (const float*)d_in[14];

    short* qx = (short*)d_ws;              // 4096*768  query bf16
    short* kx = qx + (long)4096 * 768;     // 8192*768  key bf16
    short* vx = kx + (long)8192 * 768;     // 8192*768  value bf16
    short* wq = vx + (long)8192 * 768;     // 768*768 x4 weights
    short* wk = wq + (long)768 * 768;
    short* wv = wk + (long)768 * 768;
    short* wo = wv + (long)768 * 768;
    short* qb = wo + (long)768 * 768;      // 4096*768  Q proj
    short* kb = qb + (long)4096 * 768;     // 8192*768  K proj
    short* vb = kb + (long)8192 * 768;     // 8192*768  V proj
    short* ctxb = qx;                      // reuse: qx dead after Q proj
    short* vt   = kx;                      // reuse: kx dead after K proj
    float* hbuf = (float*)vx;              // reuse: vx dead after V proj

    float* out0  = (float*)d_out;
    float* probs = out0 + (long)NB * LQ * HIDDEN;

    // all 7 fp32->bf16 conversions in one launch
    cvt_all<<<17664, 256, 0, stream>>>(query, key, value, Wq, Wk, Wv, Wo,
                                       qx, kx, vx, wq, wk, wv, wo);

    // Q/K/V projections in one launch (bf16 out)
    qkv_gemm<<<dim3(6, 160), 256, 0, stream>>>(
        qx, kx, vx, wq, wk, wv, bq, bk, bv, qb, kb, vb);

    transpose_v<<<dim3(4, 96), 256, 0, stream>>>(vb, vt);

    fused_attn<<<dim3(32, 96), 256, 0, stream>>>(qb, kb, vt, amask, probs, ctxb);

    gemm_nt_mfma<<<dim3(6, 32), 256, 0, stream>>>(
        ctxb, wo, hbuf, nullptr, bo, query, HIDDEN, HIDDEN, HIDDEN, HIDDEN, 1.0f);

    layernorm_rows<<<NB * LQ, 256, 0, stream>>>(hbuf, gamma, beta, out0);
}